// Round 2
// baseline (153.448 us; speedup 1.0000x reference)
//
#include <hip/hip_runtime.h>
#include <cstdint>

// LEVEL_SIZES = {256,128,64,32,16}, B=16, N=64 boxes, C=8, img 1024x1024
#define NBOX 64
#define NB   16
#define NC   8
#define NBLK 1664
#define EPSF 1e-8f

// ws layout:
//   [0 .. 26624)        float partials[1664][4]  (bce, p_sum, pt_sum, t_cnt) -- per-block private, no init needed
//   [26624 .. 26628)    uint finish counter      -- zeroed by k_init each call

__device__ __forceinline__ unsigned long long range_mask(int a, int e, int base) {
    int lo = a - base; lo = lo < 0 ? 0 : (lo > 64 ? 64 : lo);
    int hi = e - base; hi = hi < 0 ? 0 : (hi > 64 ? 64 : hi);
    if (hi <= lo) return 0ULL;
    unsigned long long hm = (hi >= 64) ? ~0ULL : ((1ULL << hi) - 1ULL);
    unsigned long long lm = (1ULL << lo) - 1ULL;
    return hm & ~lm;
}

__global__ void k_init(unsigned int* __restrict__ counter) {
    if (threadIdx.x == 0) *counter = 0u;
}

__global__ __launch_bounds__(256)
void k_main(const float* __restrict__ a0, const float* __restrict__ a1,
            const float* __restrict__ a2, const float* __restrict__ a3,
            const float* __restrict__ a4,
            const float* __restrict__ bboxs,
            const int* __restrict__ ih_p, const int* __restrict__ iw_p,
            const int* __restrict__ alpha_p, const int* __restrict__ beta_p,
            float* __restrict__ partials, unsigned int* __restrict__ counter,
            float* __restrict__ out) {
    const int bid = blockIdx.x;
    int l, rel;
    if      (bid < 1024) { l = 0; rel = bid; }
    else if (bid < 1280) { l = 1; rel = bid - 1024; }
    else if (bid < 1408) { l = 2; rel = bid - 1280; }
    else if (bid < 1536) { l = 3; rel = bid - 1408; }
    else                 { l = 4; rel = bid - 1536; }
    const int ntl[5] = {8, 2, 1, 1, 1};
    const int nt = ntl[l];
    const int tile = rel % nt;
    const int bc = rel / nt;
    const int c = bc & 7, b = bc >> 3;
    const int Hl = 256 >> l;
    const int P  = Hl * Hl;
    const int logW = 8 - l;
    const int W64 = (Hl >= 64) ? (Hl >> 6) : 1;

    const float w = (float)iw_p[0], h = (float)ih_p[0];
    const int alpha = alpha_p[0], beta = beta_p[0];
    const float side = (float)(1 << (l + alpha));
    const float min_a = side * side;
    const float sb = side * (float)beta;
    const float max_a = sb * sb;
    const float sx = (float)Hl / w;
    const float sy = (float)Hl / h;

    __shared__ int rx1[NBOX], rx2[NBOX], ry1[NBOX], ry2[NBOX];
    __shared__ unsigned long long rowm[64][4];
    __shared__ float redf[4][4];
    __shared__ int last_flag;
    __shared__ float pimg[NB];

    const int tid = threadIdx.x;

    // 1) box rects for this (b, l)
    if (tid < NBOX) {
        const float* bb = bboxs + (size_t)(b * NBOX + tid) * 4;
        float x1 = bb[0], y1 = bb[1], x2 = bb[2], y2 = bb[3];
        bool valid = (x1 <= w) && (y1 <= h) && (x2 <= w) && (y2 <= h);
        float area = fabsf((x2 - x1) * (y2 - y1));
        bool sel = valid && (area >= min_a) && (area <= max_a);
        rx1[tid] = (int)fmaxf(floorf(x1 * sx), 0.f);
        rx2[tid] = (int)fminf(ceilf(x2 * sx) + 1.f, (float)Hl);
        int yi1 = (int)fmaxf(floorf(y1 * sy), 0.f);
        int yi2 = (int)fminf(ceilf(y2 * sy) + 1.f, (float)Hl);
        ry1[tid] = sel ? yi1 : 0;
        ry2[tid] = sel ? yi2 : 0;   // empty range when not selected
    }
    __syncthreads();

    // 2) row coverage bitmasks for this tile's rows (in LDS)
    const int tpx = (P < 8192) ? P : 8192;       // pixels per tile
    const int start = tile * 8192;
    const int end = start + tpx;
    const int r0 = start >> logW;
    const int nrows = tpx >> logW;               // 32/64/64/32/16
    float my_t = 0.f;
    if (tid < nrows) {
        const int hh = r0 + tid;
        unsigned long long m0 = 0, m1 = 0, m2 = 0, m3 = 0;
        for (int n = 0; n < NBOX; ++n) {
            if (hh >= ry1[n] && hh < ry2[n]) {
                int a = rx1[n], e = rx2[n];
                m0 |= range_mask(a, e, 0);
                m1 |= range_mask(a, e, 64);
                m2 |= range_mask(a, e, 128);
                m3 |= range_mask(a, e, 192);
            }
        }
        rowm[tid][0] = m0;
        rowm[tid][1] = m1;
        rowm[tid][2] = m2;
        rowm[tid][3] = m3;
        my_t = (float)(__popcll(m0) + __popcll(m1) + __popcll(m2) + __popcll(m3));
    }
    __syncthreads();

    // 3) scan p with mask-bit lookup
    const float* attn = (l == 0) ? a0 : (l == 1) ? a1 : (l == 2) ? a2 : (l == 3) ? a3 : a4;
    const float* p = attn + (size_t)(b * NC + c) * P;

    float bce = 0.f, ps = 0.f, pts = 0.f;
    for (int i = start + tid * 4; i < end; i += 1024) {
        float4 v = *(const float4*)(p + i);
        int hr = (i >> logW) - r0;
        int ww = i & (Hl - 1);
        unsigned long long wd = rowm[hr][ww >> 6];
        unsigned int bits = (unsigned int)(wd >> (ww & 63)) & 0xFu;
        { float pv = v.x; bool t = bits & 1u; bce -= __logf(t ? pv : 1.f - pv); ps += pv; if (t) pts += pv; }
        { float pv = v.y; bool t = bits & 2u; bce -= __logf(t ? pv : 1.f - pv); ps += pv; if (t) pts += pv; }
        { float pv = v.z; bool t = bits & 4u; bce -= __logf(t ? pv : 1.f - pv); ps += pv; if (t) pts += pv; }
        { float pv = v.w; bool t = bits & 8u; bce -= __logf(t ? pv : 1.f - pv); ps += pv; if (t) pts += pv; }
    }

    // 4) block reduce (bce, ps, pts, t)
    for (int off = 32; off > 0; off >>= 1) {
        bce  += __shfl_down(bce,  off, 64);
        ps   += __shfl_down(ps,   off, 64);
        pts  += __shfl_down(pts,  off, 64);
        my_t += __shfl_down(my_t, off, 64);
    }
    if ((tid & 63) == 0) {
        int wv = tid >> 6;
        redf[wv][0] = bce; redf[wv][1] = ps; redf[wv][2] = pts; redf[wv][3] = my_t;
    }
    __syncthreads();
    if (tid == 0) {
        float* slot = partials + (size_t)bid * 4;
        slot[0] = redf[0][0] + redf[1][0] + redf[2][0] + redf[3][0];
        slot[1] = redf[0][1] + redf[1][1] + redf[2][1] + redf[3][1];
        slot[2] = redf[0][2] + redf[1][2] + redf[2][2] + redf[3][2];
        slot[3] = redf[0][3] + redf[1][3] + redf[2][3] + redf[3][3];
        __threadfence();                       // release partials
        unsigned int old = atomicAdd(counter, 1u);
        last_flag = (old == NBLK - 1) ? 1 : 0;
    }
    __syncthreads();

    // 5) last block computes the final scalar
    if (last_flag) {
        __threadfence();                       // acquire all partials
        if (tid < NB) pimg[tid] = 0.f;
        __syncthreads();
        const int lvl_base[5] = {0, 1024, 1280, 1408, 1536};
        for (int combo = tid; combo < 640; combo += 256) {
            int cl = combo >> 7;               // level
            int cbc = combo & 127;             // b*8 + c
            int cnt = ntl[cl];
            const float* s0 = partials + (size_t)(lvl_base[cl] + cbc * cnt) * 4;
            float sb_ = 0.f, sp = 0.f, st = 0.f, sc = 0.f;
            for (int t = 0; t < cnt; ++t) {
                sb_ += s0[t * 4 + 0];
                sp  += s0[t * 4 + 1];
                st  += s0[t * 4 + 2];
                sc  += s0[t * 4 + 3];
            }
            int HH = 256 >> cl;
            float invP = 1.f / (float)(HH * HH);
            float dice = 1.f - (2.f * st + EPSF) / (sp + sc + EPSF);
            float loss = 0.5f * sb_ * invP + 0.5f * dice;
            atomicAdd(&pimg[cbc >> 3], loss);
        }
        __syncthreads();
        if (tid < NB) {
            const int bb_ = tid;
            bool has = false;
            const float* bb = bboxs + (size_t)bb_ * NBOX * 4;
            for (int n = 0; n < NBOX; ++n) {
                float x1 = bb[n * 4 + 0], y1 = bb[n * 4 + 1];
                float x2 = bb[n * 4 + 2], y2 = bb[n * 4 + 3];
                if (x1 <= w && y1 <= h && x2 <= w && y2 <= h) { has = true; break; }
            }
            pimg[bb_] = has ? pimg[bb_] * (1.f / 40.f) : 0.f;
        }
        __syncthreads();
        if (tid == 0) {
            float t = 0.f;
            for (int i = 0; i < NB; ++i) t += pimg[i];
            out[0] = t * (1.f / (float)NB);
        }
    }
}

extern "C" void kernel_launch(void* const* d_in, const int* in_sizes, int n_in,
                              void* d_out, int out_size, void* d_ws, size_t ws_size,
                              hipStream_t stream) {
    const float* a0 = (const float*)d_in[0];
    const float* a1 = (const float*)d_in[1];
    const float* a2 = (const float*)d_in[2];
    const float* a3 = (const float*)d_in[3];
    const float* a4 = (const float*)d_in[4];
    const float* bboxs = (const float*)d_in[5];
    const int* ih = (const int*)d_in[6];
    const int* iw = (const int*)d_in[7];
    const int* al = (const int*)d_in[8];
    const int* be = (const int*)d_in[9];

    float* partials = (float*)d_ws;
    unsigned int* counter = (unsigned int*)((char*)d_ws + NBLK * 4 * sizeof(float));

    k_init<<<1, 64, 0, stream>>>(counter);
    k_main<<<NBLK, 256, 0, stream>>>(a0, a1, a2, a3, a4, bboxs, ih, iw, al, be,
                                     partials, counter, (float*)d_out);
}

// Round 3
// 118.232 us; speedup vs baseline: 1.2979x; 1.2979x over previous
//
#include <hip/hip_runtime.h>
#include <cstdint>

// LEVEL_SIZES = {256,128,64,32,16}, B=16, N=64 boxes, C=8, img 1024x1024
#define NBOX 64
#define NB   16
#define NC   8
#define EPSF 1e-8f
#define LN2F 0.69314718055994531f

// ws layout:
//   [0 .. 10240)  float acc[5][16][8][4]  (bce_ln_sum, p_sum, pt_sum, t_cnt) -- memset 0 each call

__device__ __forceinline__ unsigned long long range_mask(int a, int e, int base) {
    int lo = a - base; lo = lo < 0 ? 0 : (lo > 64 ? 64 : lo);
    int hi = e - base; hi = hi < 0 ? 0 : (hi > 64 ? 64 : hi);
    if (hi <= lo) return 0ULL;
    unsigned long long hm = (hi >= 64) ? ~0ULL : ((1ULL << hi) - 1ULL);
    unsigned long long lm = (1ULL << lo) - 1ULL;
    return hm & ~lm;
}

struct SharedBuf {
    int rx1[NBOX], rx2[NBOX], ry1[NBOX], ry2[NBOX];
    unsigned long long rowm[64][4];
    float red[4][4];
};

template<int LVL>
__device__ __forceinline__ void scan_level(
    SharedBuf& sh, int rel,
    const float* __restrict__ attn, const float* __restrict__ bboxs,
    float w, float h, int alpha, int beta, float* __restrict__ acc)
{
    constexpr int Hl   = 256 >> LVL;
    constexpr int P    = Hl * Hl;
    constexpr int TPX  = (P < 4096) ? P : 4096;   // pixels per tile
    constexpr int NT   = P / TPX;                 // tiles per (b,c)
    constexpr int NROWS = TPX / Hl;               // rows per tile
    constexpr int LOGW = 8 - LVL;
    constexpr int W64  = (Hl >= 64) ? (Hl / 64) : 1;
    constexpr int NBATCH = (TPX + 1023) / 1024;   // float4 batches per thread

    const int tile = (NT == 1) ? 0 : (rel % NT);
    const int bc   = (NT == 1) ? rel : (rel / NT);
    const int c = bc & 7, b = bc >> 3;
    const int tid = threadIdx.x;

    const float side  = (float)(1 << (LVL + alpha));
    const float min_a = side * side;
    const float sbb   = side * (float)beta;
    const float max_a = sbb * sbb;
    const float sx = (float)Hl / w;
    const float sy = (float)Hl / h;

    // 1) box rects for this (b, LVL)
    if (tid < NBOX) {
        const float* bb = bboxs + (size_t)(b * NBOX + tid) * 4;
        float x1 = bb[0], y1 = bb[1], x2 = bb[2], y2 = bb[3];
        bool valid = (x1 <= w) && (y1 <= h) && (x2 <= w) && (y2 <= h);
        float area = fabsf((x2 - x1) * (y2 - y1));
        bool sel = valid && (area >= min_a) && (area <= max_a);
        sh.rx1[tid] = (int)fmaxf(floorf(x1 * sx), 0.f);
        sh.rx2[tid] = (int)fminf(ceilf(x2 * sx) + 1.f, (float)Hl);
        int yi1 = (int)fmaxf(floorf(y1 * sy), 0.f);
        int yi2 = (int)fminf(ceilf(y2 * sy) + 1.f, (float)Hl);
        sh.ry1[tid] = sel ? yi1 : 0;
        sh.ry2[tid] = sel ? yi2 : 0;   // empty range when not selected
    }
    __syncthreads();

    // 2) row coverage bitmasks for this tile's rows
    const int start = tile * TPX;
    const int r0    = tile * NROWS;
    float my_t = 0.f;
    if (tid < NROWS) {
        const int hh = r0 + tid;
        unsigned long long m0 = 0, m1 = 0, m2 = 0, m3 = 0;
        for (int n = 0; n < NBOX; ++n) {
            if (hh >= sh.ry1[n] && hh < sh.ry2[n]) {
                int a = sh.rx1[n], e = sh.rx2[n];
                m0 |= range_mask(a, e, 0);
                if (W64 > 1) m1 |= range_mask(a, e, 64);
                if (W64 > 2) { m2 |= range_mask(a, e, 128); m3 |= range_mask(a, e, 192); }
            }
        }
        sh.rowm[tid][0] = m0; my_t += (float)__popcll(m0);
        if (W64 > 1) { sh.rowm[tid][1] = m1; my_t += (float)__popcll(m1); }
        if (W64 > 2) { sh.rowm[tid][2] = m2; my_t += (float)__popcll(m2);
                       sh.rowm[tid][3] = m3; my_t += (float)__popcll(m3); }
    }
    __syncthreads();

    // 3) batched scan: issue all loads first (MLP), then process
    const float* p = attn + (size_t)(b * NC + c) * P;
    float4 v[NBATCH];
#pragma unroll
    for (int k = 0; k < NBATCH; ++k) {
        int off = k * 1024 + tid * 4;
        if (off < TPX) v[k] = *(const float4*)(p + start + off);
    }

    float l2s[NBATCH], psA[NBATCH], ptA[NBATCH];
#pragma unroll
    for (int k = 0; k < NBATCH; ++k) { l2s[k] = 0.f; psA[k] = 0.f; ptA[k] = 0.f; }

#pragma unroll
    for (int k = 0; k < NBATCH; ++k) {
        int off = k * 1024 + tid * 4;
        if (off < TPX) {
            int i = start + off;
            int hr = (i >> LOGW) - r0;
            int ww = i & (Hl - 1);
            unsigned long long wd = sh.rowm[hr][(W64 == 1) ? 0 : (ww >> 6)];
            unsigned int bits = (unsigned int)(wd >> (ww & 63)) & 0xFu;
            float4 vv = v[k];
            { float pv = vv.x; bool t = bits & 1u; l2s[k] -= __log2f(t ? pv : 1.f - pv); psA[k] += pv; if (t) ptA[k] += pv; }
            { float pv = vv.y; bool t = bits & 2u; l2s[k] -= __log2f(t ? pv : 1.f - pv); psA[k] += pv; if (t) ptA[k] += pv; }
            { float pv = vv.z; bool t = bits & 4u; l2s[k] -= __log2f(t ? pv : 1.f - pv); psA[k] += pv; if (t) ptA[k] += pv; }
            { float pv = vv.w; bool t = bits & 8u; l2s[k] -= __log2f(t ? pv : 1.f - pv); psA[k] += pv; if (t) ptA[k] += pv; }
        }
    }

    float bce = 0.f, psum = 0.f, ptsum = 0.f;
#pragma unroll
    for (int k = 0; k < NBATCH; ++k) { bce += l2s[k]; psum += psA[k]; ptsum += ptA[k]; }
    bce *= LN2F;

    // 4) wave + block reduce (bce, psum, ptsum, my_t)
    for (int off = 32; off > 0; off >>= 1) {
        bce   += __shfl_down(bce,   off, 64);
        psum  += __shfl_down(psum,  off, 64);
        ptsum += __shfl_down(ptsum, off, 64);
        my_t  += __shfl_down(my_t,  off, 64);
    }
    if ((tid & 63) == 0) {
        int wv = tid >> 6;
        sh.red[wv][0] = bce; sh.red[wv][1] = psum; sh.red[wv][2] = ptsum; sh.red[wv][3] = my_t;
    }
    __syncthreads();
    if (tid == 0) {
        float* dst = acc + ((size_t)((LVL * NB + b) * NC + c)) * 4;
        atomicAdd(dst + 0, sh.red[0][0] + sh.red[1][0] + sh.red[2][0] + sh.red[3][0]);
        atomicAdd(dst + 1, sh.red[0][1] + sh.red[1][1] + sh.red[2][1] + sh.red[3][1]);
        atomicAdd(dst + 2, sh.red[0][2] + sh.red[1][2] + sh.red[2][2] + sh.red[3][2]);
        atomicAdd(dst + 3, sh.red[0][3] + sh.red[1][3] + sh.red[2][3] + sh.red[3][3]);
    }
}

__global__ __launch_bounds__(256)
void k_scan(const float* __restrict__ a0, const float* __restrict__ a1,
            const float* __restrict__ a2, const float* __restrict__ a3,
            const float* __restrict__ a4,
            const float* __restrict__ bboxs,
            const int* __restrict__ ih_p, const int* __restrict__ iw_p,
            const int* __restrict__ alpha_p, const int* __restrict__ beta_p,
            float* __restrict__ acc) {
    __shared__ SharedBuf sh;
    const float w = (float)iw_p[0], h = (float)ih_p[0];
    const int alpha = alpha_p[0], beta = beta_p[0];
    const int bid = blockIdx.x;
    // level segments: l0 [0,2048) l1 [2048,2560) l2 [2560,2688) l3 [2688,2816) l4 [2816,2944)
    if      (bid < 2048) scan_level<0>(sh, bid,        a0, bboxs, w, h, alpha, beta, acc);
    else if (bid < 2560) scan_level<1>(sh, bid - 2048, a1, bboxs, w, h, alpha, beta, acc);
    else if (bid < 2688) scan_level<2>(sh, bid - 2560, a2, bboxs, w, h, alpha, beta, acc);
    else if (bid < 2816) scan_level<3>(sh, bid - 2688, a3, bboxs, w, h, alpha, beta, acc);
    else                 scan_level<4>(sh, bid - 2816, a4, bboxs, w, h, alpha, beta, acc);
}

__global__ void k_final(const float* __restrict__ acc,
                        const float* __restrict__ bboxs,
                        const int* __restrict__ ih_p, const int* __restrict__ iw_p,
                        float* __restrict__ out) {
    const int tid = threadIdx.x;   // 256 threads
    __shared__ float pimg[NB];
    const float w = (float)iw_p[0], h = (float)ih_p[0];
    if (tid < NB) pimg[tid] = 0.f;
    __syncthreads();
    for (int combo = tid; combo < 640; combo += 256) {
        int l = combo >> 7;            // level
        int bc = combo & 127;          // b*8 + c
        const float* a = acc + (size_t)combo * 4;
        int HH = 256 >> l;
        float invP = 1.f / (float)(HH * HH);
        float bce = a[0] * invP;
        float dice = 1.f - (2.f * a[2] + EPSF) / (a[1] + a[3] + EPSF);
        atomicAdd(&pimg[bc >> 3], 0.5f * bce + 0.5f * dice);
    }
    __syncthreads();
    if (tid < NB) {
        const int b = tid;
        bool has = false;
        const float* bb = bboxs + (size_t)b * NBOX * 4;
        for (int n = 0; n < NBOX; ++n) {
            float x1 = bb[n * 4 + 0], y1 = bb[n * 4 + 1];
            float x2 = bb[n * 4 + 2], y2 = bb[n * 4 + 3];
            if (x1 <= w && y1 <= h && x2 <= w && y2 <= h) { has = true; break; }
        }
        pimg[b] = has ? pimg[b] * (1.f / 40.f) : 0.f;
    }
    __syncthreads();
    if (tid == 0) {
        float t = 0.f;
        for (int i = 0; i < NB; ++i) t += pimg[i];
        out[0] = t * (1.f / (float)NB);
    }
}

extern "C" void kernel_launch(void* const* d_in, const int* in_sizes, int n_in,
                              void* d_out, int out_size, void* d_ws, size_t ws_size,
                              hipStream_t stream) {
    const float* a0 = (const float*)d_in[0];
    const float* a1 = (const float*)d_in[1];
    const float* a2 = (const float*)d_in[2];
    const float* a3 = (const float*)d_in[3];
    const float* a4 = (const float*)d_in[4];
    const float* bboxs = (const float*)d_in[5];
    const int* ih = (const int*)d_in[6];
    const int* iw = (const int*)d_in[7];
    const int* al = (const int*)d_in[8];
    const int* be = (const int*)d_in[9];

    float* acc = (float*)d_ws;   // 2560 floats

    hipMemsetAsync(acc, 0, 2560 * sizeof(float), stream);
    k_scan<<<2944, 256, 0, stream>>>(a0, a1, a2, a3, a4, bboxs, ih, iw, al, be, acc);
    k_final<<<1, 256, 0, stream>>>(acc, bboxs, ih, iw, (float*)d_out);
}

// Round 4
// 105.473 us; speedup vs baseline: 1.4549x; 1.1210x over previous
//
#include <hip/hip_runtime.h>
#include <cstdint>

// LEVEL_SIZES = {256,128,64,32,16}, B=16, N=64 boxes, C=8, img 1024x1024
#define NBOX 64
#define NB   16
#define NC   8
#define EPSF 1e-8f
#define LN2F 0.69314718055994531f

// ws layout:
//   [0 .. 47104)  float4 partials[2944]  (bce_sum, p_sum, pt_sum, t_cnt)
//   per-block private slots -- every block writes its slot every call, no init needed.

__device__ __forceinline__ unsigned long long range_mask(int a, int e, int base) {
    int lo = a - base; lo = lo < 0 ? 0 : (lo > 64 ? 64 : lo);
    int hi = e - base; hi = hi < 0 ? 0 : (hi > 64 ? 64 : hi);
    if (hi <= lo) return 0ULL;
    unsigned long long hm = (hi >= 64) ? ~0ULL : ((1ULL << hi) - 1ULL);
    unsigned long long lm = (1ULL << lo) - 1ULL;
    return hm & ~lm;
}

struct SharedBuf {
    int rx1[NBOX], rx2[NBOX], ry1[NBOX], ry2[NBOX];
    unsigned long long rowm[64];     // flat [NROWS][W64], NROWS*W64 <= 64 at every level
    float red[4][4];
};

template<int LVL>
__device__ __forceinline__ void scan_level(
    SharedBuf& sh, int rel, int bid,
    const float* __restrict__ attn, const float* __restrict__ bboxs,
    float w, float h, int alpha, int beta, float4* __restrict__ partials)
{
    constexpr int Hl    = 256 >> LVL;
    constexpr int P     = Hl * Hl;
    constexpr int TPX   = (P < 4096) ? P : 4096;   // pixels per tile
    constexpr int NT    = P / TPX;                 // tiles per (b,c)
    constexpr int NROWS = TPX / Hl;                // rows per tile (16..64)
    constexpr int LOGW  = 8 - LVL;
    constexpr int W64   = (Hl >= 64) ? (Hl / 64) : 1;
    constexpr int NBATCH = (TPX + 1023) / 1024;    // float4 batches per thread

    const int tile = (NT == 1) ? 0 : (rel % NT);
    const int bc   = (NT == 1) ? rel : (rel / NT);
    const int c = bc & 7, b = bc >> 3;
    const int tid = threadIdx.x;
    const int start = tile * TPX;
    const int r0    = tile * NROWS;

    // ---- 1) issue ALL attn loads first; latency hides under mask work ----
    const float* p = attn + (size_t)(b * NC + c) * P + start;
    float4 v[NBATCH];
#pragma unroll
    for (int k = 0; k < NBATCH; ++k) {
        int off = k * 1024 + tid * 4;
        if (off < TPX) v[k] = *(const float4*)(p + off);
    }

    // ---- 2) rects (wave 0) + rowm zero, overlapped with loads in flight ----
    if (tid < NROWS * W64) sh.rowm[tid] = 0ULL;
    if (tid < NBOX) {
        const float side  = (float)(1 << (LVL + alpha));
        const float min_a = side * side;
        const float sbb   = side * (float)beta;
        const float max_a = sbb * sbb;
        const float sx = (float)Hl / w;
        const float sy = (float)Hl / h;
        float4 bb = *(const float4*)(bboxs + (size_t)(b * NBOX + tid) * 4);
        bool valid = (bb.x <= w) && (bb.y <= h) && (bb.z <= w) && (bb.w <= h);
        float area = fabsf((bb.z - bb.x) * (bb.w - bb.y));
        bool sel = valid && (area >= min_a) && (area <= max_a);
        sh.rx1[tid] = (int)fmaxf(floorf(bb.x * sx), 0.f);
        sh.rx2[tid] = (int)fminf(ceilf(bb.z * sx) + 1.f, (float)Hl);
        int yi1 = (int)fmaxf(floorf(bb.y * sy), 0.f);
        int yi2 = (int)fminf(ceilf(bb.w * sy) + 1.f, (float)Hl);
        sh.ry1[tid] = sel ? yi1 : 0;
        sh.ry2[tid] = sel ? yi2 : 0;   // empty range when not selected
    }
    __syncthreads();

    // ---- 3) mask build, 4 waves x 16 boxes each, ds_or combine ----
    {
        const int g = tid >> 6;        // == wave id
        const int r = tid & 63;
        if (r < NROWS) {
            const int hh = r0 + r;
            unsigned long long m[W64];
#pragma unroll
            for (int wi = 0; wi < W64; ++wi) m[wi] = 0ULL;
            const int n0 = g * 16;
            for (int n = n0; n < n0 + 16; ++n) {
                if (hh >= sh.ry1[n] && hh < sh.ry2[n]) {
                    int a = sh.rx1[n], e = sh.rx2[n];
#pragma unroll
                    for (int wi = 0; wi < W64; ++wi) m[wi] |= range_mask(a, e, wi * 64);
                }
            }
#pragma unroll
            for (int wi = 0; wi < W64; ++wi)
                if (m[wi]) atomicOr(&sh.rowm[r * W64 + wi], m[wi]);
        }
    }
    __syncthreads();

    // ---- 4) t-count rides on row popcounts ----
    float my_t = 0.f;
    if (tid < NROWS) {
#pragma unroll
        for (int wi = 0; wi < W64; ++wi)
            my_t += (float)__popcll(sh.rowm[tid * W64 + wi]);
    }

    // ---- 5) consume loads: independent accumulator sets per batch ----
    float l2s[NBATCH], psA[NBATCH], ptA[NBATCH];
#pragma unroll
    for (int k = 0; k < NBATCH; ++k) { l2s[k] = 0.f; psA[k] = 0.f; ptA[k] = 0.f; }
#pragma unroll
    for (int k = 0; k < NBATCH; ++k) {
        int off = k * 1024 + tid * 4;
        if (off < TPX) {
            int hr = off >> LOGW;              // local row in tile
            int ww = off & (Hl - 1);
            unsigned long long wd = sh.rowm[hr * W64 + ((W64 == 1) ? 0 : (ww >> 6))];
            unsigned int bits = (unsigned int)(wd >> (ww & 63)) & 0xFu;
            float4 vv = v[k];
            { float pv = vv.x; bool t = bits & 1u; l2s[k] -= __log2f(t ? pv : 1.f - pv); psA[k] += pv; if (t) ptA[k] += pv; }
            { float pv = vv.y; bool t = bits & 2u; l2s[k] -= __log2f(t ? pv : 1.f - pv); psA[k] += pv; if (t) ptA[k] += pv; }
            { float pv = vv.z; bool t = bits & 4u; l2s[k] -= __log2f(t ? pv : 1.f - pv); psA[k] += pv; if (t) ptA[k] += pv; }
            { float pv = vv.w; bool t = bits & 8u; l2s[k] -= __log2f(t ? pv : 1.f - pv); psA[k] += pv; if (t) ptA[k] += pv; }
        }
    }
    float bce = 0.f, psum = 0.f, ptsum = 0.f;
#pragma unroll
    for (int k = 0; k < NBATCH; ++k) { bce += l2s[k]; psum += psA[k]; ptsum += ptA[k]; }

    // ---- 6) wave + block reduce; private slot write (no atomics) ----
    for (int off = 32; off > 0; off >>= 1) {
        bce   += __shfl_down(bce,   off, 64);
        psum  += __shfl_down(psum,  off, 64);
        ptsum += __shfl_down(ptsum, off, 64);
        my_t  += __shfl_down(my_t,  off, 64);
    }
    if ((tid & 63) == 0) {
        int wv = tid >> 6;
        sh.red[wv][0] = bce; sh.red[wv][1] = psum; sh.red[wv][2] = ptsum; sh.red[wv][3] = my_t;
    }
    __syncthreads();
    if (tid == 0) {
        float4 o;
        o.x = (sh.red[0][0] + sh.red[1][0] + sh.red[2][0] + sh.red[3][0]) * LN2F;
        o.y =  sh.red[0][1] + sh.red[1][1] + sh.red[2][1] + sh.red[3][1];
        o.z =  sh.red[0][2] + sh.red[1][2] + sh.red[2][2] + sh.red[3][2];
        o.w =  sh.red[0][3] + sh.red[1][3] + sh.red[2][3] + sh.red[3][3];
        partials[bid] = o;
    }
}

__global__ __launch_bounds__(256)
void k_scan(const float* __restrict__ a0, const float* __restrict__ a1,
            const float* __restrict__ a2, const float* __restrict__ a3,
            const float* __restrict__ a4,
            const float* __restrict__ bboxs,
            const int* __restrict__ ih_p, const int* __restrict__ iw_p,
            const int* __restrict__ alpha_p, const int* __restrict__ beta_p,
            float4* __restrict__ partials) {
    __shared__ SharedBuf sh;
    const float w = (float)iw_p[0], h = (float)ih_p[0];
    const int alpha = alpha_p[0], beta = beta_p[0];
    const int bid = blockIdx.x;
    // level segments: l0 [0,2048) l1 [2048,2560) l2 [2560,2688) l3 [2688,2816) l4 [2816,2944)
    if      (bid < 2048) scan_level<0>(sh, bid,        bid, a0, bboxs, w, h, alpha, beta, partials);
    else if (bid < 2560) scan_level<1>(sh, bid - 2048, bid, a1, bboxs, w, h, alpha, beta, partials);
    else if (bid < 2688) scan_level<2>(sh, bid - 2560, bid, a2, bboxs, w, h, alpha, beta, partials);
    else if (bid < 2816) scan_level<3>(sh, bid - 2688, bid, a3, bboxs, w, h, alpha, beta, partials);
    else                 scan_level<4>(sh, bid - 2816, bid, a4, bboxs, w, h, alpha, beta, partials);
}

__global__ void k_final(const float4* __restrict__ partials,
                        const float* __restrict__ bboxs,
                        const int* __restrict__ ih_p, const int* __restrict__ iw_p,
                        float* __restrict__ out) {
    const int tid = threadIdx.x;   // 256 threads
    __shared__ float pimg[NB];
    const float w = (float)iw_p[0], h = (float)ih_p[0];
    if (tid < NB) pimg[tid] = 0.f;
    __syncthreads();
    const int ntl[5]  = {16, 4, 1, 1, 1};
    const int base[5] = {0, 2048, 2560, 2688, 2816};
    for (int combo = tid; combo < 640; combo += 256) {
        int l  = combo >> 7;           // level
        int bc = combo & 127;          // b*8 + c
        int cnt = ntl[l];
        const float4* s0 = partials + base[l] + bc * cnt;
        float sb = 0.f, sp = 0.f, st = 0.f, sc = 0.f;
        for (int t = 0; t < cnt; ++t) {
            float4 x = s0[t];
            sb += x.x; sp += x.y; st += x.z; sc += x.w;
        }
        int HH = 256 >> l;
        float invP = 1.f / (float)(HH * HH);
        float dice = 1.f - (2.f * st + EPSF) / (sp + sc + EPSF);
        atomicAdd(&pimg[bc >> 3], 0.5f * sb * invP + 0.5f * dice);
    }
    __syncthreads();
    if (tid < NB) {
        const int b = tid;
        bool has = false;
        const float* bb = bboxs + (size_t)b * NBOX * 4;
        for (int n = 0; n < NBOX; ++n) {
            float x1 = bb[n * 4 + 0], y1 = bb[n * 4 + 1];
            float x2 = bb[n * 4 + 2], y2 = bb[n * 4 + 3];
            if (x1 <= w && y1 <= h && x2 <= w && y2 <= h) { has = true; break; }
        }
        pimg[b] = has ? pimg[b] * (1.f / 40.f) : 0.f;
    }
    __syncthreads();
    if (tid == 0) {
        float t = 0.f;
        for (int i = 0; i < NB; ++i) t += pimg[i];
        out[0] = t * (1.f / (float)NB);
    }
}

extern "C" void kernel_launch(void* const* d_in, const int* in_sizes, int n_in,
                              void* d_out, int out_size, void* d_ws, size_t ws_size,
                              hipStream_t stream) {
    const float* a0 = (const float*)d_in[0];
    const float* a1 = (const float*)d_in[1];
    const float* a2 = (const float*)d_in[2];
    const float* a3 = (const float*)d_in[3];
    const float* a4 = (const float*)d_in[4];
    const float* bboxs = (const float*)d_in[5];
    const int* ih = (const int*)d_in[6];
    const int* iw = (const int*)d_in[7];
    const int* al = (const int*)d_in[8];
    const int* be = (const int*)d_in[9];

    float4* partials = (float4*)d_ws;   // 2944 slots, all rewritten every call

    k_scan<<<2944, 256, 0, stream>>>(a0, a1, a2, a3, a4, bboxs, ih, iw, al, be, partials);
    k_final<<<1, 256, 0, stream>>>(partials, bboxs, ih, iw, (float*)d_out);
}

// Round 5
// 103.139 us; speedup vs baseline: 1.4878x; 1.0226x over previous
//
#include <hip/hip_runtime.h>
#include <cstdint>

// LEVEL_SIZES = {256,128,64,32,16}, B=16, N=64 boxes, C=8, img 1024x1024
#define NBOX 64
#define NB   16
#define NC   8
#define EPSF 1e-8f
#define LN2F 0.69314718055994531f

// ws layout:
//   [0 .. 26624)  float4 partials[1664]  (bce_sum, p_sum, pt_sum, t_cnt)
//   per-block private slots -- every block writes its slot every call, no init needed.
//
// grid layout (1664 blocks):
//   L0 [0,1024):    16*8 maps x 8 tiles of 8192 px   (Hl=256)
//   L1 [1024,1280): 16*8 maps x 2 tiles of 8192 px   (Hl=128)
//   L2 [1280,1408): 16*8 maps x 1 tile  of 4096 px   (Hl=64)
//   L3 [1408,1536): 16*8 maps x 1 tile  of 1024 px   (Hl=32)
//   L4 [1536,1664): 16*8 maps x 1 tile  of  256 px   (Hl=16)

__device__ __forceinline__ unsigned long long range_mask(int a, int e, int base) {
    int lo = a - base; lo = lo < 0 ? 0 : (lo > 64 ? 64 : lo);
    int hi = e - base; hi = hi < 0 ? 0 : (hi > 64 ? 64 : hi);
    if (hi <= lo) return 0ULL;
    unsigned long long hm = (hi >= 64) ? ~0ULL : ((1ULL << hi) - 1ULL);
    unsigned long long lm = (1ULL << lo) - 1ULL;
    return hm & ~lm;
}

struct SharedBuf {
    int rx1[NBOX], rx2[NBOX], ry1[NBOX], ry2[NBOX];
    unsigned long long rowm[128];    // flat [NROWS][W64], NROWS*W64 <= 128 at every level
    float red[4][4];
};

template<int LVL>
__device__ __forceinline__ void scan_level(
    SharedBuf& sh, int rel, int bid,
    const float* __restrict__ attn, const float* __restrict__ bboxs,
    float w, float h, int alpha, int beta, float4* __restrict__ partials)
{
    constexpr int Hl    = 256 >> LVL;
    constexpr int P     = Hl * Hl;
    constexpr int TPX   = (P < 8192) ? P : 8192;   // pixels per tile
    constexpr int NT    = P / TPX;                 // tiles per (b,c)
    constexpr int NROWS = TPX / Hl;                // rows per tile (16..64)
    constexpr int LOGW  = 8 - LVL;
    constexpr int W64   = (Hl >= 64) ? (Hl / 64) : 1;
    constexpr int NBATCH = (TPX + 1023) / 1024;    // float4 batches per thread (<=8)

    const int tile = (NT == 1) ? 0 : (rel % NT);
    const int bc   = (NT == 1) ? rel : (rel / NT);
    const int c = bc & 7, b = bc >> 3;
    const int tid = threadIdx.x;
    const int start = tile * TPX;
    const int r0    = tile * NROWS;

    // ---- 1) issue ALL attn loads first; latency hides under mask work ----
    const float* p = attn + (size_t)(b * NC + c) * P + start;
    float4 v[NBATCH];
#pragma unroll
    for (int k = 0; k < NBATCH; ++k) {
        int off = k * 1024 + tid * 4;
        if (off < TPX) v[k] = *(const float4*)(p + off);
    }

    // ---- 2) rects (wave 0) + rowm zero, overlapped with loads in flight ----
    if (tid < NROWS * W64) sh.rowm[tid] = 0ULL;
    if (tid < NBOX) {
        const float side  = (float)(1 << (LVL + alpha));
        const float min_a = side * side;
        const float sbb   = side * (float)beta;
        const float max_a = sbb * sbb;
        const float sx = (float)Hl / w;
        const float sy = (float)Hl / h;
        float4 bb = *(const float4*)(bboxs + (size_t)(b * NBOX + tid) * 4);
        bool valid = (bb.x <= w) && (bb.y <= h) && (bb.z <= w) && (bb.w <= h);
        float area = fabsf((bb.z - bb.x) * (bb.w - bb.y));
        bool sel = valid && (area >= min_a) && (area <= max_a);
        sh.rx1[tid] = (int)fmaxf(floorf(bb.x * sx), 0.f);
        sh.rx2[tid] = (int)fminf(ceilf(bb.z * sx) + 1.f, (float)Hl);
        int yi1 = (int)fmaxf(floorf(bb.y * sy), 0.f);
        int yi2 = (int)fminf(ceilf(bb.w * sy) + 1.f, (float)Hl);
        sh.ry1[tid] = sel ? yi1 : 0;
        sh.ry2[tid] = sel ? yi2 : 0;   // empty range when not selected
    }
    __syncthreads();

    // ---- 3) mask build, 4 waves x 16 boxes each, ds_or combine ----
    {
        const int g = tid >> 6;        // wave id
        const int r = tid & 63;
        if (r < NROWS) {
            const int hh = r0 + r;
            unsigned long long m[W64];
#pragma unroll
            for (int wi = 0; wi < W64; ++wi) m[wi] = 0ULL;
            const int n0 = g * 16;
            for (int n = n0; n < n0 + 16; ++n) {
                if (hh >= sh.ry1[n] && hh < sh.ry2[n]) {
                    int a = sh.rx1[n], e = sh.rx2[n];
#pragma unroll
                    for (int wi = 0; wi < W64; ++wi) m[wi] |= range_mask(a, e, wi * 64);
                }
            }
#pragma unroll
            for (int wi = 0; wi < W64; ++wi)
                if (m[wi]) atomicOr(&sh.rowm[r * W64 + wi], m[wi]);
        }
    }
    __syncthreads();

    // ---- 4) t-count rides on row popcounts ----
    float my_t = 0.f;
    if (tid < NROWS) {
#pragma unroll
        for (int wi = 0; wi < W64; ++wi)
            my_t += (float)__popcll(sh.rowm[tid * W64 + wi]);
    }

    // ---- 5) consume loads: 2 rotating accumulator sets (VGPR-lean, chain-split) ----
    float l2s[2], psA[2], ptA[2];
    l2s[0] = l2s[1] = psA[0] = psA[1] = ptA[0] = ptA[1] = 0.f;
#pragma unroll
    for (int k = 0; k < NBATCH; ++k) {
        int off = k * 1024 + tid * 4;
        if (off < TPX) {
            int s = k & 1;
            int hr = off >> LOGW;              // local row in tile
            int ww = off & (Hl - 1);
            unsigned long long wd = sh.rowm[hr * W64 + ((W64 == 1) ? 0 : (ww >> 6))];
            unsigned int bits = (unsigned int)(wd >> (ww & 63)) & 0xFu;
            float4 vv = v[k];
            { float pv = vv.x; bool t = bits & 1u; l2s[s] -= __log2f(t ? pv : 1.f - pv); psA[s] += pv; if (t) ptA[s] += pv; }
            { float pv = vv.y; bool t = bits & 2u; l2s[s] -= __log2f(t ? pv : 1.f - pv); psA[s] += pv; if (t) ptA[s] += pv; }
            { float pv = vv.z; bool t = bits & 4u; l2s[s] -= __log2f(t ? pv : 1.f - pv); psA[s] += pv; if (t) ptA[s] += pv; }
            { float pv = vv.w; bool t = bits & 8u; l2s[s] -= __log2f(t ? pv : 1.f - pv); psA[s] += pv; if (t) ptA[s] += pv; }
        }
    }
    float bce = l2s[0] + l2s[1];
    float psum = psA[0] + psA[1];
    float ptsum = ptA[0] + ptA[1];

    // ---- 6) wave + block reduce; private slot write (no atomics) ----
    for (int off = 32; off > 0; off >>= 1) {
        bce   += __shfl_down(bce,   off, 64);
        psum  += __shfl_down(psum,  off, 64);
        ptsum += __shfl_down(ptsum, off, 64);
        my_t  += __shfl_down(my_t,  off, 64);
    }
    if ((tid & 63) == 0) {
        int wv = tid >> 6;
        sh.red[wv][0] = bce; sh.red[wv][1] = psum; sh.red[wv][2] = ptsum; sh.red[wv][3] = my_t;
    }
    __syncthreads();
    if (tid == 0) {
        float4 o;
        o.x = (sh.red[0][0] + sh.red[1][0] + sh.red[2][0] + sh.red[3][0]) * LN2F;
        o.y =  sh.red[0][1] + sh.red[1][1] + sh.red[2][1] + sh.red[3][1];
        o.z =  sh.red[0][2] + sh.red[1][2] + sh.red[2][2] + sh.red[3][2];
        o.w =  sh.red[0][3] + sh.red[1][3] + sh.red[2][3] + sh.red[3][3];
        partials[bid] = o;
    }
}

__global__ __launch_bounds__(256)
void k_scan(const float* __restrict__ a0, const float* __restrict__ a1,
            const float* __restrict__ a2, const float* __restrict__ a3,
            const float* __restrict__ a4,
            const float* __restrict__ bboxs,
            const int* __restrict__ ih_p, const int* __restrict__ iw_p,
            const int* __restrict__ alpha_p, const int* __restrict__ beta_p,
            float4* __restrict__ partials) {
    __shared__ SharedBuf sh;
    const float w = (float)iw_p[0], h = (float)ih_p[0];
    const int alpha = alpha_p[0], beta = beta_p[0];
    const int bid = blockIdx.x;
    if      (bid < 1024) scan_level<0>(sh, bid,        bid, a0, bboxs, w, h, alpha, beta, partials);
    else if (bid < 1280) scan_level<1>(sh, bid - 1024, bid, a1, bboxs, w, h, alpha, beta, partials);
    else if (bid < 1408) scan_level<2>(sh, bid - 1280, bid, a2, bboxs, w, h, alpha, beta, partials);
    else if (bid < 1536) scan_level<3>(sh, bid - 1408, bid, a3, bboxs, w, h, alpha, beta, partials);
    else                 scan_level<4>(sh, bid - 1536, bid, a4, bboxs, w, h, alpha, beta, partials);
}

__global__ void k_final(const float4* __restrict__ partials,
                        const float* __restrict__ bboxs,
                        const int* __restrict__ ih_p, const int* __restrict__ iw_p,
                        float* __restrict__ out) {
    const int tid = threadIdx.x;   // 256 threads
    __shared__ float pimg[NB];
    const float w = (float)iw_p[0], h = (float)ih_p[0];
    if (tid < NB) pimg[tid] = 0.f;
    __syncthreads();
    const int ntl[5]  = {8, 2, 1, 1, 1};
    const int base[5] = {0, 1024, 1280, 1408, 1536};
    for (int combo = tid; combo < 640; combo += 256) {
        int l  = combo >> 7;           // level
        int bc = combo & 127;          // b*8 + c
        int cnt = ntl[l];
        const float4* s0 = partials + base[l] + bc * cnt;
        float sb = 0.f, sp = 0.f, st = 0.f, sc = 0.f;
        for (int t = 0; t < cnt; ++t) {
            float4 x = s0[t];
            sb += x.x; sp += x.y; st += x.z; sc += x.w;
        }
        int HH = 256 >> l;
        float invP = 1.f / (float)(HH * HH);
        float dice = 1.f - (2.f * st + EPSF) / (sp + sc + EPSF);
        atomicAdd(&pimg[bc >> 3], 0.5f * sb * invP + 0.5f * dice);
    }
    __syncthreads();
    if (tid < NB) {
        const int b = tid;
        bool has = false;
        const float* bb = bboxs + (size_t)b * NBOX * 4;
        for (int n = 0; n < NBOX; ++n) {
            float x1 = bb[n * 4 + 0], y1 = bb[n * 4 + 1];
            float x2 = bb[n * 4 + 2], y2 = bb[n * 4 + 3];
            if (x1 <= w && y1 <= h && x2 <= w && y2 <= h) { has = true; break; }
        }
        pimg[b] = has ? pimg[b] * (1.f / 40.f) : 0.f;
    }
    __syncthreads();
    if (tid == 0) {
        float t = 0.f;
        for (int i = 0; i < NB; ++i) t += pimg[i];
        out[0] = t * (1.f / (float)NB);
    }
}

extern "C" void kernel_launch(void* const* d_in, const int* in_sizes, int n_in,
                              void* d_out, int out_size, void* d_ws, size_t ws_size,
                              hipStream_t stream) {
    const float* a0 = (const float*)d_in[0];
    const float* a1 = (const float*)d_in[1];
    const float* a2 = (const float*)d_in[2];
    const float* a3 = (const float*)d_in[3];
    const float* a4 = (const float*)d_in[4];
    const float* bboxs = (const float*)d_in[5];
    const int* ih = (const int*)d_in[6];
    const int* iw = (const int*)d_in[7];
    const int* al = (const int*)d_in[8];
    const int* be = (const int*)d_in[9];

    float4* partials = (float4*)d_ws;   // 1664 slots, all rewritten every call

    k_scan<<<1664, 256, 0, stream>>>(a0, a1, a2, a3, a4, bboxs, ih, iw, al, be, partials);
    k_final<<<1, 256, 0, stream>>>(partials, bboxs, ih, iw, (float*)d_out);
}